// Round 4
// baseline (452.024 us; speedup 1.0000x reference)
//
#include <hip/hip_runtime.h>
#include <stdint.h>

typedef __attribute__((ext_vector_type(8))) short bh8;       // 8 x bf16 (4 VGPR)
typedef __attribute__((ext_vector_type(4))) float f32x4;
typedef __attribute__((ext_vector_type(4))) unsigned short u16x4;
typedef __attribute__((ext_vector_type(8))) unsigned short u16x8;

#define DEVI static __device__ __forceinline__

constexpr int B_ = 2, S_ = 2048, D_ = 1024, H_ = 16, E_ = 64;

// workspace layout (elements of ushort/bf16)
constexpr size_t OFF_XB  = 0;                              // x as bf16 [B*S, D]
constexpr size_t OFF_WQT = OFF_XB  + (size_t)B_*S_*D_;     // WqT [H, E, D]
constexpr size_t OFF_WKT = OFF_WQT + (size_t)H_*E_*D_;
constexpr size_t OFF_WVT = OFF_WKT + (size_t)H_*E_*D_;
constexpr size_t OFF_WOT = OFF_WVT + (size_t)H_*E_*D_;     // WoT [D, D]
constexpr size_t OFF_Q   = OFF_WOT + (size_t)D_*D_;        // [B*H, S, E]  (pre-scaled by 0.125*log2e)
constexpr size_t OFF_K   = OFF_Q   + (size_t)B_*H_*S_*E_;  // [B*H, S, E]
constexpr size_t OFF_VT  = OFF_K   + (size_t)B_*H_*S_*E_;  // [B*H, E, S]
constexpr size_t OFF_O   = OFF_VT  + (size_t)B_*H_*S_*E_;  // attn out concat [B*S, D]

DEVI unsigned short f2bf(float f) {
    union { float f; unsigned u; } v; v.f = f;
    unsigned u = v.u;
    return (unsigned short)((u + 0x7fffu + ((u >> 16) & 1u)) >> 16);
}

DEVI f32x4 mfma16(bh8 a, bh8 b, f32x4 c) {
    return __builtin_amdgcn_mfma_f32_16x16x32_bf16(a, b, c, 0, 0, 0);
}

DEVI float redmax16(float v) {
    v = fmaxf(v, __shfl_xor(v, 1, 64));
    v = fmaxf(v, __shfl_xor(v, 2, 64));
    v = fmaxf(v, __shfl_xor(v, 4, 64));
    v = fmaxf(v, __shfl_xor(v, 8, 64));
    return v;
}
DEVI float redsum16(float v) {
    v += __shfl_xor(v, 1, 64);
    v += __shfl_xor(v, 2, 64);
    v += __shfl_xor(v, 4, 64);
    v += __shfl_xor(v, 8, 64);
    return v;
}

// ---------------- prep: x -> bf16 ----------------
__global__ __launch_bounds__(256) void k_convert_x(const float* __restrict__ x,
                                                   unsigned short* __restrict__ ws) {
    const int i = blockIdx.x * 256 + threadIdx.x;   // one float4 each; n4 = 1048576
    const float4 v = ((const float4*)x)[i];
    u16x4 o = { f2bf(v.x), f2bf(v.y), f2bf(v.z), f2bf(v.w) };
    *(u16x4*)(ws + OFF_XB + (size_t)i * 4) = o;
}

// ---------------- prep: weights -> bf16, transposed ----------------
__global__ __launch_bounds__(256) void k_transpose_w(const float* __restrict__ Wq,
                                                     const float* __restrict__ Wk,
                                                     const float* __restrict__ Wv,
                                                     const float* __restrict__ Wo,
                                                     unsigned short* __restrict__ ws) {
    const int xi = blockIdx.x;   // 0..255
    const int z  = blockIdx.y;   // 0..3
    const int t  = threadIdx.x;
    __shared__ __align__(16) unsigned short tile[64][72];

    const float* src; unsigned short* dst;
    int inCols, inBase, outBase;
    if (z < 3) {
        src = (z == 0) ? Wq : (z == 1) ? Wk : Wv;
        dst = ws + ((z == 0) ? OFF_WQT : (z == 1) ? OFF_WKT : OFF_WVT);
        inCols = 64;
        inBase = xi * 64 * 64;
        const int h = xi >> 4, dt = xi & 15;
        outBase = h * 65536 + dt * 64;
    } else {
        src = Wo; dst = ws + OFF_WOT;
        inCols = 1024;
        const int et = xi >> 4, dt = xi & 15;
        inBase  = (dt * 64) * 1024 + et * 64;
        outBase = (et * 64) * 1024 + dt * 64;
    }
#pragma unroll
    for (int v = 0; v < 4; ++v) {
        const int flat = v * 256 + t;
        const int i = flat >> 4, j4 = (flat & 15) * 4;
        const float4 val = *(const float4*)(src + inBase + i * inCols + j4);
        tile[i][j4 + 0] = f2bf(val.x);
        tile[i][j4 + 1] = f2bf(val.y);
        tile[i][j4 + 2] = f2bf(val.z);
        tile[i][j4 + 3] = f2bf(val.w);
    }
    __syncthreads();
    const int j = t >> 2, iseg = (t & 3) * 16;
    u16x8 p0, p1;
#pragma unroll
    for (int u = 0; u < 8; ++u) p0[u] = tile[iseg + u][j];
#pragma unroll
    for (int u = 0; u < 8; ++u) p1[u] = tile[iseg + 8 + u][j];
    *(u16x8*)(dst + outBase + (size_t)j * 1024 + iseg)     = p0;
    *(u16x8*)(dst + outBase + (size_t)j * 1024 + iseg + 8) = p1;
}

// ---------------- barrier-free reg-direct GEMM: C(128x64) = A(128x1024) * B^T(64x1024)^T
// Each wave owns 32 output rows; fragments loaded straight to VGPRs.
// One base per fragment stream; all 32 K-steps are imm offsets (ks*64B <= 1984).
DEVI void gemm_reg_128x64(const unsigned short* __restrict__ A,
                          const unsigned short* __restrict__ Bw,
                          f32x4 acc[2][4]) {
    const int lane = threadIdx.x & 63;
    const int w    = threadIdx.x >> 6;
    const int lr = lane & 15, lg = lane >> 4;
    const unsigned short* pa0 = A  + (size_t)(w * 32 +  0 + lr) * D_ + lg * 8;
    const unsigned short* pa1 = A  + (size_t)(w * 32 + 16 + lr) * D_ + lg * 8;
    const unsigned short* pb0 = Bw + (size_t)( 0 + lr) * D_ + lg * 8;
    const unsigned short* pb1 = Bw + (size_t)(16 + lr) * D_ + lg * 8;
    const unsigned short* pb2 = Bw + (size_t)(32 + lr) * D_ + lg * 8;
    const unsigned short* pb3 = Bw + (size_t)(48 + lr) * D_ + lg * 8;
#pragma unroll
    for (int ks = 0; ks < 32; ++ks) {
        const int o = ks * 32;
        bh8 af0 = *(const bh8*)(pa0 + o);
        bh8 af1 = *(const bh8*)(pa1 + o);
        bh8 bf0 = *(const bh8*)(pb0 + o);
        bh8 bf1 = *(const bh8*)(pb1 + o);
        bh8 bf2 = *(const bh8*)(pb2 + o);
        bh8 bf3 = *(const bh8*)(pb3 + o);
        acc[0][0] = mfma16(af0, bf0, acc[0][0]);
        acc[1][0] = mfma16(af1, bf0, acc[1][0]);
        acc[0][1] = mfma16(af0, bf1, acc[0][1]);
        acc[1][1] = mfma16(af1, bf1, acc[1][1]);
        acc[0][2] = mfma16(af0, bf2, acc[0][2]);
        acc[1][2] = mfma16(af1, bf2, acc[1][2]);
        acc[0][3] = mfma16(af0, bf3, acc[0][3]);
        acc[1][3] = mfma16(af1, bf3, acc[1][3]);
    }
}

// ---------------- QKV projection ----------------
__global__ __launch_bounds__(256, 4) void k_qkv(unsigned short* __restrict__ ws,
                                                const float* __restrict__ bq,
                                                const float* __restrict__ bk,
                                                const float* __restrict__ bv) {
    const int stile = blockIdx.x;   // 0..31
    const int h     = blockIdx.y;   // 0..15
    const int mat   = blockIdx.z;   // 0=Q 1=K 2=V
    const int row0  = stile * 128;
    const int b     = row0 >> 11;
    const int bh    = b * H_ + h;
    const unsigned short* A  = ws + OFF_XB + (size_t)row0 * D_;
    const unsigned short* Bw = ws + ((mat == 0) ? OFF_WQT : (mat == 1) ? OFF_WKT : OFF_WVT)
                                  + (size_t)h * E_ * D_;
    const float* bias = ((mat == 0) ? bq : (mat == 1) ? bk : bv) + h * E_;

    f32x4 acc[2][4];
#pragma unroll
    for (int i = 0; i < 2; ++i)
#pragma unroll
        for (int j = 0; j < 4; ++j) acc[i][j] = (f32x4){0.f, 0.f, 0.f, 0.f};

    gemm_reg_128x64(A, Bw, acc);

    const int lane = threadIdx.x & 63, w = threadIdx.x >> 6;
    const int lr = lane & 15, lg = lane >> 4;
    const int srow0 = row0 + w * 32;
    const int sl0   = srow0 & (S_ - 1);
#pragma unroll
    for (int mt = 0; mt < 2; ++mt) {
#pragma unroll
        for (int nt = 0; nt < 4; ++nt) {
            const int e = nt * 16 + lr;
            const float bia = bias[e];
            if (mat == 2) {
                u16x4 pk;
#pragma unroll
                for (int r = 0; r < 4; ++r) pk[r] = f2bf(acc[mt][nt][r] + bia);
                const int sl = sl0 + mt * 16 + lg * 4;
                *(u16x4*)(ws + OFF_VT + ((size_t)(bh * E_ + e)) * S_ + sl) = pk;
            } else {
#pragma unroll
                for (int r = 0; r < 4; ++r) {
                    float v = acc[mt][nt][r] + bia;
                    const int sl = sl0 + mt * 16 + lg * 4 + r;
                    if (mat == 0)   // fold 1/sqrt(64) * log2(e) into Q
                        ws[OFF_Q + ((size_t)bh * S_ + sl) * E_ + e] = f2bf(v * 0.1803368801f);
                    else
                        ws[OFF_K + ((size_t)bh * S_ + sl) * E_ + e] = f2bf(v);
                }
            }
        }
    }
}

// ---------------- flash attention (causal), barrier-free, 16 q-rows/wave ----------------
// K/V fragments go straight to VGPRs (no LDS staging, no __syncthreads anywhere).
// Pipeline: issue V -> QK^T (kills K regs) -> issue next K -> softmax -> P->LDS -> PV.
// Compiler emits counted vmcnt waits from the dependency graph; 12 waves/CU drift freely.
__global__ __launch_bounds__(256, 3) void k_attn(unsigned short* __restrict__ ws) {
    const int qt = 31 - blockIdx.x;  // heavy tiles first (0..31, 64 q rows each)
    const int bh = blockIdx.y;       // 0..31
    const int lane = threadIdx.x & 63, w = threadIdx.x >> 6;
    const int lr = lane & 15, lg = lane >> 4;
    const unsigned short* Qp = ws + OFF_Q  + (size_t)bh * S_ * E_;
    const unsigned short* Kp = ws + OFF_K  + (size_t)bh * S_ * E_;
    const unsigned short* Vp = ws + OFF_VT + (size_t)bh * E_ * S_;
    __shared__ __align__(16) unsigned short ldsP[4 * 1024];   // per-wave 16x64 P (wave-private)

    const int qbase = qt * 64 + w * 16;   // this wave's 16 q rows
    bh8 qf[2];
#pragma unroll
    for (int kg = 0; kg < 2; ++kg)
        qf[kg] = *(const bh8*)(Qp + (size_t)(qbase + lr) * E_ + kg * 32 + lg * 8);

    f32x4 o[4];
    float m[4], l[4];
#pragma unroll
    for (int i = 0; i < 4; ++i) {
        o[i] = (f32x4){0.f, 0.f, 0.f, 0.f};
        m[i] = -3.0e38f; l[i] = 0.f;
    }

    // fragment base pointers (advance per k-tile)
    const unsigned short* kp = Kp + (size_t)lr * E_ + lg * 8;        // += 64*E_ per kt
    const unsigned short* vp = Vp + (size_t)lr * S_ + lg * 8;        // += 64 per kt

    // prologue: K tile 0 into regs
    bh8 kf[4][2];
#pragma unroll
    for (int ct = 0; ct < 4; ++ct)
#pragma unroll
        for (int kg = 0; kg < 2; ++kg)
            kf[ct][kg] = *(const bh8*)(kp + (ct * 16) * E_ + kg * 32);
    kp += 64 * E_;

    unsigned short* Pw = ldsP + w * 1024;

    for (int kt = 0; kt <= qt; ++kt) {
        // issue V loads for this tile (in flight under QK^T + softmax)
        bh8 vf[4][2];
#pragma unroll
        for (int et = 0; et < 4; ++et)
#pragma unroll
            for (int kg = 0; kg < 2; ++kg)
                vf[et][kg] = *(const bh8*)(vp + (size_t)(et * 16) * S_ + kg * 32);
        vp += 64;

        // S = Q K^T (Q pre-scaled by 0.125*log2e -> scores in log2 domain)
        f32x4 sc[4];
#pragma unroll
        for (int ct = 0; ct < 4; ++ct) sc[ct] = (f32x4){0.f, 0.f, 0.f, 0.f};
#pragma unroll
        for (int ct = 0; ct < 4; ++ct)
#pragma unroll
            for (int kg = 0; kg < 2; ++kg)
                sc[ct] = mfma16(qf[kg], kf[ct][kg], sc[ct]);

        // K regs now dead -> issue next tile's K loads (fly under softmax/PV)
        if (kt < qt) {
#pragma unroll
            for (int ct = 0; ct < 4; ++ct)
#pragma unroll
                for (int kg = 0; kg < 2; ++kg)
                    kf[ct][kg] = *(const bh8*)(kp + (ct * 16) * E_ + kg * 32);
            kp += 64 * E_;
        }

        // causal mask: only the diagonal tile needs it (kt == qt)
        if (kt == qt) {
            const int sk0 = kt * 64;
#pragma unroll
            for (int ct = 0; ct < 4; ++ct) {
                const int skc = sk0 + ct * 16 + lr;
#pragma unroll
                for (int r = 0; r < 4; ++r) {
                    const int sq = qbase + lg * 4 + r;
                    if (skc > sq) sc[ct][r] = -3.0e38f;
                }
            }
        }
        // online softmax: row max over 16 lanes
        float mx[4];
#pragma unroll
        for (int r = 0; r < 4; ++r) {
            float v = fmaxf(fmaxf(sc[0][r], sc[1][r]), fmaxf(sc[2][r], sc[3][r]));
            mx[r] = redmax16(v);
        }
        bool need = false;
#pragma unroll
        for (int r = 0; r < 4; ++r) need |= (mx[r] > m[r]);
        if (__any(need)) {   // rescale is identity when mx<=m for all rows
#pragma unroll
            for (int r = 0; r < 4; ++r) {
                const float mn = fmaxf(m[r], mx[r]);
                const float sf = __builtin_amdgcn_exp2f(m[r] - mn);
                m[r] = mn;
                l[r] *= sf;
#pragma unroll
                for (int et = 0; et < 4; ++et) o[et][r] *= sf;
            }
        }
        // P = exp2(S - m), row sums
        float rs[4];
#pragma unroll
        for (int r = 0; r < 4; ++r) rs[r] = 0.f;
#pragma unroll
        for (int ct = 0; ct < 4; ++ct)
#pragma unroll
            for (int r = 0; r < 4; ++r) {
                float p = __builtin_amdgcn_exp2f(sc[ct][r] - m[r]);
                sc[ct][r] = p;
                rs[r] += p;
            }
#pragma unroll
        for (int r = 0; r < 4; ++r) l[r] += redsum16(rs[r]);
        // write P (bf16) into per-wave LDS in A-frag order (lgkmcnt-ordered, no barrier)
#pragma unroll
        for (int ct = 0; ct < 4; ++ct) {
            const int blk = ct >> 1;
            const int lanep = ((ct & 1) * 2 + (lr >> 3)) * 16;
            const int elem = lr & 7;
#pragma unroll
            for (int r = 0; r < 4; ++r)
                Pw[blk * 512 + (lanep + lg * 4 + r) * 8 + elem] = f2bf(sc[ct][r]);
        }
        // O += P V
#pragma unroll
        for (int skg = 0; skg < 2; ++skg) {
            bh8 pf = *(const bh8*)(Pw + skg * 512 + lane * 8);
#pragma unroll
            for (int et = 0; et < 4; ++et)
                o[et] = mfma16(pf, vf[et][skg], o[et]);
        }
    }
    // epilogue: O/l -> concat layout [B,S,H*64]
    const int b = bh >> 4, hh = bh & 15;
#pragma unroll
    for (int r = 0; r < 4; ++r) {
        const float inv = 1.0f / l[r];
        const int s = qbase + lg * 4 + r;
#pragma unroll
        for (int et = 0; et < 4; ++et)
            ws[OFF_O + ((size_t)(b * S_ + s)) * D_ + hh * E_ + et * 16 + lr] =
                f2bf(o[et][r] * inv);
    }
}

// ---------------- output projection ----------------
__global__ __launch_bounds__(256, 4) void k_oproj(const unsigned short* __restrict__ ws,
                                                  const float* __restrict__ bo,
                                                  float* __restrict__ out) {
    const int stile = blockIdx.x;   // 0..31
    const int ntile = blockIdx.y;   // 0..15
    const unsigned short* A  = ws + OFF_O   + (size_t)stile * 128 * D_;
    const unsigned short* Bw = ws + OFF_WOT + (size_t)ntile * 64 * D_;
    f32x4 acc[2][4];
#pragma unroll
    for (int i = 0; i < 2; ++i)
#pragma unroll
        for (int j = 0; j < 4; ++j) acc[i][j] = (f32x4){0.f, 0.f, 0.f, 0.f};

    gemm_reg_128x64(A, Bw, acc);

    const int lane = threadIdx.x & 63, w = threadIdx.x >> 6;
    const int lr = lane & 15, lg = lane >> 4;
    const int r0 = stile * 128 + w * 32;
#pragma unroll
    for (int mt = 0; mt < 2; ++mt)
#pragma unroll
        for (int nt = 0; nt < 4; ++nt) {
            const int e = ntile * 64 + nt * 16 + lr;
            const float bia = bo[e];
#pragma unroll
            for (int r = 0; r < 4; ++r)
                out[(size_t)(r0 + mt * 16 + lg * 4 + r) * D_ + e] = acc[mt][nt][r] + bia;
        }
}

extern "C" void kernel_launch(void* const* d_in, const int* in_sizes, int n_in,
                              void* d_out, int out_size, void* d_ws, size_t ws_size,
                              hipStream_t stream) {
    const float* x  = (const float*)d_in[0];
    const float* Wq = (const float*)d_in[1];
    const float* bq = (const float*)d_in[2];
    const float* Wk = (const float*)d_in[3];
    const float* bk = (const float*)d_in[4];
    const float* Wv = (const float*)d_in[5];
    const float* bv = (const float*)d_in[6];
    const float* Wo = (const float*)d_in[7];
    const float* bo = (const float*)d_in[8];
    float* out = (float*)d_out;
    unsigned short* ws = (unsigned short*)d_ws;

    k_convert_x<<<dim3((B_ * S_ * D_) / 4 / 256), 256, 0, stream>>>(x, ws);
    k_transpose_w<<<dim3(256, 4), 256, 0, stream>>>(Wq, Wk, Wv, Wo, ws);
    k_qkv<<<dim3(32, 16, 3), 256, 0, stream>>>(ws, bq, bk, bv);
    k_attn<<<dim3(32, 32), 256, 0, stream>>>(ws);
    k_oproj<<<dim3(32, 16), 256, 0, stream>>>(ws, bo, out);
}

// Round 5
// 207.393 us; speedup vs baseline: 2.1796x; 2.1796x over previous
//
#include <hip/hip_runtime.h>
#include <stdint.h>

typedef __attribute__((ext_vector_type(8))) short bh8;       // 8 x bf16 (4 VGPR)
typedef __attribute__((ext_vector_type(4))) float f32x4;
typedef __attribute__((ext_vector_type(4))) unsigned short u16x4;
typedef __attribute__((ext_vector_type(8))) unsigned short u16x8;

#define DEVI static __device__ __forceinline__

constexpr int B_ = 2, S_ = 2048, D_ = 1024, H_ = 16, E_ = 64;

// workspace layout (elements of ushort/bf16)
constexpr size_t OFF_XB  = 0;                              // x as bf16 [B*S, D]
constexpr size_t OFF_WQT = OFF_XB  + (size_t)B_*S_*D_;     // WqT [H, E, D]
constexpr size_t OFF_WKT = OFF_WQT + (size_t)H_*E_*D_;
constexpr size_t OFF_WVT = OFF_WKT + (size_t)H_*E_*D_;
constexpr size_t OFF_WOT = OFF_WVT + (size_t)H_*E_*D_;     // WoT [D, D]
constexpr size_t OFF_Q   = OFF_WOT + (size_t)D_*D_;        // [B*H, S, E]  (pre-scaled by 0.125*log2e)
constexpr size_t OFF_K   = OFF_Q   + (size_t)B_*H_*S_*E_;  // [B*H, S, E]
constexpr size_t OFF_VT  = OFF_K   + (size_t)B_*H_*S_*E_;  // [B*H, E, S]
constexpr size_t OFF_O   = OFF_VT  + (size_t)B_*H_*S_*E_;  // attn out concat [B*S, D]

DEVI unsigned short f2bf(float f) {
    union { float f; unsigned u; } v; v.f = f;
    unsigned u = v.u;
    return (unsigned short)((u + 0x7fffu + ((u >> 16) & 1u)) >> 16);
}

DEVI void gload16(const void* g, void* l) {
    __builtin_amdgcn_global_load_lds(
        (const __attribute__((address_space(1))) unsigned int*)g,
        (__attribute__((address_space(3))) unsigned int*)l, 16, 0, 0);
}

DEVI f32x4 mfma16(bh8 a, bh8 b, f32x4 c) {
    return __builtin_amdgcn_mfma_f32_16x16x32_bf16(a, b, c, 0, 0, 0);
}

// counted-vmcnt barrier: prefetched loads stay in flight across the barrier.
// sched_barrier(0) pins LDS reads below the barrier (they must not hoist above:
// other waves' staging completes only at the barrier rendezvous).
template<int N> DEVI void vm_barrier() {
    asm volatile("s_waitcnt vmcnt(%0)" :: "i"(N) : "memory");
    __builtin_amdgcn_s_barrier();
    __builtin_amdgcn_sched_barrier(0);
}
// post-compute barrier: pins this wave's LDS reads above (so staging into the
// just-read buffer can't start early), and staging below.
DEVI void post_barrier() {
    __builtin_amdgcn_sched_barrier(0);
    __builtin_amdgcn_s_barrier();
    __builtin_amdgcn_sched_barrier(0);
}

DEVI float redmax16(float v) {
    v = fmaxf(v, __shfl_xor(v, 1, 64));
    v = fmaxf(v, __shfl_xor(v, 2, 64));
    v = fmaxf(v, __shfl_xor(v, 4, 64));
    v = fmaxf(v, __shfl_xor(v, 8, 64));
    return v;
}
DEVI float redsum16(float v) {
    v += __shfl_xor(v, 1, 64);
    v += __shfl_xor(v, 2, 64);
    v += __shfl_xor(v, 4, 64);
    v += __shfl_xor(v, 8, 64);
    return v;
}

// ---------------- prep: x -> bf16 ----------------
__global__ __launch_bounds__(256) void k_convert_x(const float* __restrict__ x,
                                                   unsigned short* __restrict__ ws) {
    const int i = blockIdx.x * 256 + threadIdx.x;   // one float4 each; n4 = 1048576
    const float4 v = ((const float4*)x)[i];
    u16x4 o = { f2bf(v.x), f2bf(v.y), f2bf(v.z), f2bf(v.w) };
    *(u16x4*)(ws + OFF_XB + (size_t)i * 4) = o;
}

// ---------------- prep: weights -> bf16, transposed ----------------
__global__ __launch_bounds__(256) void k_transpose_w(const float* __restrict__ Wq,
                                                     const float* __restrict__ Wk,
                                                     const float* __restrict__ Wv,
                                                     const float* __restrict__ Wo,
                                                     unsigned short* __restrict__ ws) {
    const int xi = blockIdx.x;   // 0..255
    const int z  = blockIdx.y;   // 0..3
    const int t  = threadIdx.x;
    __shared__ __align__(16) unsigned short tile[64][72];

    const float* src; unsigned short* dst;
    int inCols, inBase, outBase;
    if (z < 3) {
        src = (z == 0) ? Wq : (z == 1) ? Wk : Wv;
        dst = ws + ((z == 0) ? OFF_WQT : (z == 1) ? OFF_WKT : OFF_WVT);
        inCols = 64;
        inBase = xi * 64 * 64;
        const int h = xi >> 4, dt = xi & 15;
        outBase = h * 65536 + dt * 64;
    } else {
        src = Wo; dst = ws + OFF_WOT;
        inCols = 1024;
        const int et = xi >> 4, dt = xi & 15;
        inBase  = (dt * 64) * 1024 + et * 64;
        outBase = (et * 64) * 1024 + dt * 64;
    }
#pragma unroll
    for (int v = 0; v < 4; ++v) {
        const int flat = v * 256 + t;
        const int i = flat >> 4, j4 = (flat & 15) * 4;
        const float4 val = *(const float4*)(src + inBase + i * inCols + j4);
        tile[i][j4 + 0] = f2bf(val.x);
        tile[i][j4 + 1] = f2bf(val.y);
        tile[i][j4 + 2] = f2bf(val.z);
        tile[i][j4 + 3] = f2bf(val.w);
    }
    __syncthreads();
    const int j = t >> 2, iseg = (t & 3) * 16;
    u16x8 p0, p1;
#pragma unroll
    for (int u = 0; u < 8; ++u) p0[u] = tile[iseg + u][j];
#pragma unroll
    for (int u = 0; u < 8; ++u) p1[u] = tile[iseg + 8 + u][j];
    *(u16x8*)(dst + outBase + (size_t)j * 1024 + iseg)     = p0;
    *(u16x8*)(dst + outBase + (size_t)j * 1024 + iseg + 8) = p1;
}

// ---------------- GEMM mainloop: C(128x64) = A(128x1024) * B^T(64x1024)^T ----------------
// global_load_lds staging, 3 buffers, 3-deep prefetch, counted-vmcnt barriers.
// Per k-step: 3 gload16/wave -> steady state 9 in flight, wait vmcnt(6).
// lds must hold 3 * 6144 elements (36 KB).
DEVI void gemm_tile_128x64(const unsigned short* __restrict__ A,
                           const unsigned short* __restrict__ Bw,
                           unsigned short* lds,
                           f32x4 acc[2][4]) {
    const int lane = threadIdx.x & 63;
    const int w    = threadIdx.x >> 6;
    const int lr = lane & 15, lg = lane >> 4;
    const unsigned short* a0 = A  + (size_t)((w * 2 + 0) * 16 + lr) * D_ + lg * 8;
    const unsigned short* a1 = A  + (size_t)((w * 2 + 1) * 16 + lr) * D_ + lg * 8;
    const unsigned short* b0 = Bw + (size_t)(w * 16 + lr) * D_ + lg * 8;
    const int oA0 = (w * 2 + 0) * 512, oA1 = (w * 2 + 1) * 512, oB = 8 * 512 + w * 512;

    auto stage = [&](int ks, int bufi) {
        unsigned short* base = lds + bufi * 6144;
        gload16(a0 + ks * 32, base + oA0);
        gload16(a1 + ks * 32, base + oA1);
        gload16(b0 + ks * 32, base + oB);
    };

    stage(0, 0); stage(1, 1); stage(2, 2);
    for (int ks = 0; ks < 32; ++ks) {
        if (ks < 30)       vm_barrier<6>();   // tile ks landed; ks+1, ks+2 in flight
        else if (ks == 30) vm_barrier<3>();
        else               vm_barrier<0>();
        const unsigned short* base = lds + (ks % 3) * 6144;
        bh8 af0 = *(const bh8*)(base + (w * 2 + 0) * 512 + lane * 8);
        bh8 af1 = *(const bh8*)(base + (w * 2 + 1) * 512 + lane * 8);
#pragma unroll
        for (int nt = 0; nt < 4; ++nt) {
            bh8 bf = *(const bh8*)(base + 8 * 512 + nt * 512 + lane * 8);
            acc[0][nt] = mfma16(af0, bf, acc[0][nt]);
            acc[1][nt] = mfma16(af1, bf, acc[1][nt]);
        }
        post_barrier();                        // all waves done reading buf[ks%3]
        if (ks + 3 < 32) stage(ks + 3, ks % 3);
    }
}

// ---------------- QKV projection ----------------
__global__ __launch_bounds__(256, 4) void k_qkv(unsigned short* __restrict__ ws,
                                                const float* __restrict__ bq,
                                                const float* __restrict__ bk,
                                                const float* __restrict__ bv) {
    const int stile = blockIdx.x;   // 0..31
    const int h     = blockIdx.y;   // 0..15
    const int mat   = blockIdx.z;   // 0=Q 1=K 2=V
    const int row0  = stile * 128;
    const int b     = row0 >> 11;
    const int bh    = b * H_ + h;
    const unsigned short* A  = ws + OFF_XB + (size_t)row0 * D_;
    const unsigned short* Bw = ws + ((mat == 0) ? OFF_WQT : (mat == 1) ? OFF_WKT : OFF_WVT)
                                  + (size_t)h * E_ * D_;
    const float* bias = ((mat == 0) ? bq : (mat == 1) ? bk : bv) + h * E_;

    __shared__ __align__(16) unsigned short lds[3 * 6144];
    f32x4 acc[2][4];
#pragma unroll
    for (int i = 0; i < 2; ++i)
#pragma unroll
        for (int j = 0; j < 4; ++j) acc[i][j] = (f32x4){0.f, 0.f, 0.f, 0.f};

    gemm_tile_128x64(A, Bw, lds, acc);

    const int lane = threadIdx.x & 63, w = threadIdx.x >> 6;
    const int lr = lane & 15, lg = lane >> 4;
    const int srow0 = row0 + w * 32;
    const int sl0   = srow0 & (S_ - 1);
#pragma unroll
    for (int mt = 0; mt < 2; ++mt) {
#pragma unroll
        for (int nt = 0; nt < 4; ++nt) {
            const int e = nt * 16 + lr;
            const float bia = bias[e];
            if (mat == 2) {
                u16x4 pk;
#pragma unroll
                for (int r = 0; r < 4; ++r) pk[r] = f2bf(acc[mt][nt][r] + bia);
                const int sl = sl0 + mt * 16 + lg * 4;
                *(u16x4*)(ws + OFF_VT + ((size_t)(bh * E_ + e)) * S_ + sl) = pk;
            } else {
#pragma unroll
                for (int r = 0; r < 4; ++r) {
                    float v = acc[mt][nt][r] + bia;
                    const int sl = sl0 + mt * 16 + lg * 4 + r;
                    if (mat == 0)   // fold 1/sqrt(64) * log2(e) into Q
                        ws[OFF_Q + ((size_t)bh * S_ + sl) * E_ + e] = f2bf(v * 0.1803368801f);
                    else
                        ws[OFF_K + ((size_t)bh * S_ + sl) * E_ + e] = f2bf(v);
                }
            }
        }
    }
}

// ---------------- flash attention (causal), 64-row q-tiles, 16 rows/wave ----------------
// global_load_lds staging, 2 buffers, 2-deep prefetch, counted-vmcnt barriers.
// Per k-tile: 4 gload16/wave -> steady state 8 in flight, wait vmcnt(4).
__global__ __launch_bounds__(256, 4) void k_attn(unsigned short* __restrict__ ws) {
    const int qt = 31 - blockIdx.x;  // heavy tiles first (0..31, 64 q rows each)
    const int bh = blockIdx.y;       // 0..31
    const int lane = threadIdx.x & 63, w = threadIdx.x >> 6;
    const int lr = lane & 15, lg = lane >> 4;
    const unsigned short* Qp = ws + OFF_Q  + (size_t)bh * S_ * E_;
    const unsigned short* Kp = ws + OFF_K  + (size_t)bh * S_ * E_;
    const unsigned short* Vp = ws + OFF_VT + (size_t)bh * E_ * S_;
    __shared__ __align__(16) unsigned short ldsK[2][8 * 512];
    __shared__ __align__(16) unsigned short ldsV[2][8 * 512];
    __shared__ __align__(16) unsigned short ldsP[4 * 1024];   // per-wave 16x64 P (wave-private)

    const int qbase = qt * 64 + w * 16;   // this wave's 16 q rows
    bh8 qf[2];
#pragma unroll
    for (int kg = 0; kg < 2; ++kg)
        qf[kg] = *(const bh8*)(Qp + (size_t)(qbase + lr) * E_ + kg * 32 + lg * 8);

    f32x4 o[4];
    float m[4], l[4];
#pragma unroll
    for (int i = 0; i < 4; ++i) {
        o[i] = (f32x4){0.f, 0.f, 0.f, 0.f};
        m[i] = -3.0e38f; l[i] = 0.f;
    }

    auto stage = [&](int kt, int bufi) {
        const int sk0 = kt * 64;
#pragma unroll
        for (int u = 0; u < 2; ++u) {
            const int blk = w * 2 + u;
            const int ct = blk >> 1, kg = blk & 1;
            gload16(Kp + (size_t)(sk0 + ct * 16 + lr) * E_ + kg * 32 + lg * 8,
                    &ldsK[bufi][blk * 512]);
            gload16(Vp + (size_t)(ct * 16 + lr) * S_ + sk0 + kg * 32 + lg * 8,
                    &ldsV[bufi][blk * 512]);
        }
    };

    unsigned short* Pw = ldsP + w * 1024;

    stage(0, 0);
    if (qt >= 1) stage(1, 1);

    for (int kt = 0; kt <= qt; ++kt) {
        if (kt < qt) vm_barrier<4>();   // tile kt landed; kt+1 in flight
        else         vm_barrier<0>();
        const int cur = kt & 1;
        const int sk0 = kt * 64;
        const unsigned short* Kc = ldsK[cur];
        const unsigned short* Vc = ldsV[cur];

        // S = Q K^T (Q pre-scaled by 0.125*log2e -> scores in log2 domain)
        f32x4 sc[4];
#pragma unroll
        for (int ct = 0; ct < 4; ++ct) sc[ct] = (f32x4){0.f, 0.f, 0.f, 0.f};
#pragma unroll
        for (int ct = 0; ct < 4; ++ct)
#pragma unroll
            for (int kg = 0; kg < 2; ++kg) {
                bh8 kf = *(const bh8*)(Kc + (ct * 2 + kg) * 512 + lane * 8);
                sc[ct] = mfma16(qf[kg], kf, sc[ct]);
            }
        // causal mask: only the diagonal tile needs it (kt == qt)
        if (kt == qt) {
#pragma unroll
            for (int ct = 0; ct < 4; ++ct) {
                const int skc = sk0 + ct * 16 + lr;
#pragma unroll
                for (int r = 0; r < 4; ++r) {
                    const int sq = qbase + lg * 4 + r;
                    if (skc > sq) sc[ct][r] = -3.0e38f;
                }
            }
        }
        // online softmax: row max over 16 lanes
        float mx[4];
#pragma unroll
        for (int r = 0; r < 4; ++r) {
            float v = fmaxf(fmaxf(sc[0][r], sc[1][r]), fmaxf(sc[2][r], sc[3][r]));
            mx[r] = redmax16(v);
        }
        bool need = false;
#pragma unroll
        for (int r = 0; r < 4; ++r) need |= (mx[r] > m[r]);
        if (__any(need)) {   // rescale is identity when mx<=m for all rows
#pragma unroll
            for (int r = 0; r < 4; ++r) {
                const float mn = fmaxf(m[r], mx[r]);
                const float sf = __builtin_amdgcn_exp2f(m[r] - mn);
                m[r] = mn;
                l[r] *= sf;
#pragma unroll
                for (int et = 0; et < 4; ++et) o[et][r] *= sf;
            }
        }
        // P = exp2(S - m), row sums
        float rs[4];
#pragma unroll
        for (int r = 0; r < 4; ++r) rs[r] = 0.f;
#pragma unroll
        for (int ct = 0; ct < 4; ++ct)
#pragma unroll
            for (int r = 0; r < 4; ++r) {
                float p = __builtin_amdgcn_exp2f(sc[ct][r] - m[r]);
                sc[ct][r] = p;
                rs[r] += p;
            }
#pragma unroll
        for (int r = 0; r < 4; ++r) l[r] += redsum16(rs[r]);
        // write P (bf16) into per-wave LDS in A-frag order (wave-private, lgkm-ordered)
#pragma unroll
        for (int ct = 0; ct < 4; ++ct) {
            const int blk = ct >> 1;
            const int lanep = ((ct & 1) * 2 + (lr >> 3)) * 16;
            const int elem = lr & 7;
#pragma unroll
            for (int r = 0; r < 4; ++r)
                Pw[blk * 512 + (lanep + lg * 4 + r) * 8 + elem] = f2bf(sc[ct][r]);
        }
        // O += P V
#pragma unroll
        for (int skg = 0; skg < 2; ++skg) {
            bh8 pf = *(const bh8*)(Pw + skg * 512 + lane * 8);
#pragma unroll
            for (int et = 0; et < 4; ++et) {
                bh8 vf = *(const bh8*)(Vc + (et * 2 + skg) * 512 + lane * 8);
                o[et] = mfma16(pf, vf, o[et]);
            }
        }
        post_barrier();                       // all waves done reading buf[cur]
        if (kt + 2 <= qt) stage(kt + 2, cur); // refill the buffer just freed
    }
    // epilogue: O/l -> concat layout [B,S,H*64]
    const int b = bh >> 4, hh = bh & 15;
#pragma unroll
    for (int r = 0; r < 4; ++r) {
        const float inv = 1.0f / l[r];
        const int s = qbase + lg * 4 + r;
#pragma unroll
        for (int et = 0; et < 4; ++et)
            ws[OFF_O + ((size_t)(b * S_ + s)) * D_ + hh * E_ + et * 16 + lr] =
                f2bf(o[et][r] * inv);
    }
}

// ---------------- output projection ----------------
__global__ __launch_bounds__(256, 4) void k_oproj(const unsigned short* __restrict__ ws,
                                                  const float* __restrict__ bo,
                                                  float* __restrict__ out) {
    const int stile = blockIdx.x;   // 0..31
    const int ntile = blockIdx.y;   // 0..15
    const unsigned short* A  = ws + OFF_O   + (size_t)stile * 128 * D_;
    const unsigned short* Bw = ws + OFF_WOT + (size_t)ntile * 64 * D_;
    __shared__ __align__(16) unsigned short lds[3 * 6144];
    f32x4 acc[2][4];
#pragma unroll
    for (int i = 0; i < 2; ++i)
#pragma unroll
        for (int j = 0; j < 4; ++j) acc[i][j] = (f32x4){0.f, 0.f, 0.f, 0.f};

    gemm_tile_128x64(A, Bw, lds, acc);

    const int lane = threadIdx.x & 63, w = threadIdx.x >> 6;
    const int lr = lane & 15, lg = lane >> 4;
    const int r0 = stile * 128 + w * 32;
#pragma unroll
    for (int mt = 0; mt < 2; ++mt)
#pragma unroll
        for (int nt = 0; nt < 4; ++nt) {
            const int e = ntile * 64 + nt * 16 + lr;
            const float bia = bo[e];
#pragma unroll
            for (int r = 0; r < 4; ++r)
                out[(size_t)(r0 + mt * 16 + lg * 4 + r) * D_ + e] = acc[mt][nt][r] + bia;
        }
}

extern "C" void kernel_launch(void* const* d_in, const int* in_sizes, int n_in,
                              void* d_out, int out_size, void* d_ws, size_t ws_size,
                              hipStream_t stream) {
    const float* x  = (const float*)d_in[0];
    const float* Wq = (const float*)d_in[1];
    const float* bq = (const float*)d_in[2];
    const float* Wk = (const float*)d_in[3];
    const float* bk = (const float*)d_in[4];
    const float* Wv = (const float*)d_in[5];
    const float* bv = (const float*)d_in[6];
    const float* Wo = (const float*)d_in[7];
    const float* bo = (const float*)d_in[8];
    float* out = (float*)d_out;
    unsigned short* ws = (unsigned short*)d_ws;

    k_convert_x<<<dim3((B_ * S_ * D_) / 4 / 256), 256, 0, stream>>>(x, ws);
    k_transpose_w<<<dim3(256, 4), 256, 0, stream>>>(Wq, Wk, Wv, Wo, ws);
    k_qkv<<<dim3(32, 16, 3), 256, 0, stream>>>(ws, bq, bk, bv);
    k_attn<<<dim3(32, 32), 256, 0, stream>>>(ws);
    k_oproj<<<dim3(32, 16), 256, 0, stream>>>(ws, bo, out);
}

// Round 6
// 143.845 us; speedup vs baseline: 3.1424x; 1.4418x over previous
//
#include <hip/hip_runtime.h>
#include <stdint.h>

typedef __attribute__((ext_vector_type(8))) short bh8;       // 8 x bf16 (4 VGPR)
typedef __attribute__((ext_vector_type(4))) float f32x4;
typedef __attribute__((ext_vector_type(4))) unsigned short u16x4;
typedef __attribute__((ext_vector_type(8))) unsigned short u16x8;

#define DEVI static __device__ __forceinline__

constexpr int B_ = 2, S_ = 2048, D_ = 1024, H_ = 16, E_ = 64;

// workspace layout (elements of ushort/bf16)
constexpr size_t OFF_XB  = 0;                              // x as bf16 [B*S, D]
constexpr size_t OFF_WQT = OFF_XB  + (size_t)B_*S_*D_;     // WqT [H, E, D]  } contiguous
constexpr size_t OFF_WKT = OFF_WQT + (size_t)H_*E_*D_;     // WkT [H, E, D]  } = one
constexpr size_t OFF_WVT = OFF_WKT + (size_t)H_*E_*D_;     // WvT [H, E, D]  } [3072,1024]
constexpr size_t OFF_WOT = OFF_WVT + (size_t)H_*E_*D_;     // WoT [D, D]
constexpr size_t OFF_Q   = OFF_WOT + (size_t)D_*D_;        // [B*H, S, E]  (pre-scaled by 0.125*log2e)
constexpr size_t OFF_K   = OFF_Q   + (size_t)B_*H_*S_*E_;  // [B*H, S, E]
constexpr size_t OFF_VT  = OFF_K   + (size_t)B_*H_*S_*E_;  // [B*H, E, S]
constexpr size_t OFF_O   = OFF_VT  + (size_t)B_*H_*S_*E_;  // attn out concat [B*S, D]

DEVI unsigned short f2bf(float f) {
    union { float f; unsigned u; } v; v.f = f;
    unsigned u = v.u;
    return (unsigned short)((u + 0x7fffu + ((u >> 16) & 1u)) >> 16);
}

DEVI void gload16(const void* g, void* l) {
    __builtin_amdgcn_global_load_lds(
        (const __attribute__((address_space(1))) unsigned int*)g,
        (__attribute__((address_space(3))) unsigned int*)l, 16, 0, 0);
}

DEVI f32x4 mfma16(bh8 a, bh8 b, f32x4 c) {
    return __builtin_amdgcn_mfma_f32_16x16x32_bf16(a, b, c, 0, 0, 0);
}

// counted-vmcnt barrier: prefetched loads stay in flight across the barrier.
template<int N> DEVI void vm_barrier() {
    asm volatile("s_waitcnt vmcnt(%0)" :: "i"(N) : "memory");
    __builtin_amdgcn_s_barrier();
    __builtin_amdgcn_sched_barrier(0);
}
DEVI void post_barrier() {
    __builtin_amdgcn_sched_barrier(0);
    __builtin_amdgcn_s_barrier();
    __builtin_amdgcn_sched_barrier(0);
}

DEVI float redmax16(float v) {
    v = fmaxf(v, __shfl_xor(v, 1, 64));
    v = fmaxf(v, __shfl_xor(v, 2, 64));
    v = fmaxf(v, __shfl_xor(v, 4, 64));
    v = fmaxf(v, __shfl_xor(v, 8, 64));
    return v;
}
DEVI float redsum16(float v) {
    v += __shfl_xor(v, 1, 64);
    v += __shfl_xor(v, 2, 64);
    v += __shfl_xor(v, 4, 64);
    v += __shfl_xor(v, 8, 64);
    return v;
}

// ---------------- prep: x -> bf16 ----------------
__global__ __launch_bounds__(256) void k_convert_x(const float* __restrict__ x,
                                                   unsigned short* __restrict__ ws) {
    const int i = blockIdx.x * 256 + threadIdx.x;   // one float4 each; n4 = 1048576
    const float4 v = ((const float4*)x)[i];
    u16x4 o = { f2bf(v.x), f2bf(v.y), f2bf(v.z), f2bf(v.w) };
    *(u16x4*)(ws + OFF_XB + (size_t)i * 4) = o;
}

// ---------------- prep: weights -> bf16, transposed ----------------
__global__ __launch_bounds__(256) void k_transpose_w(const float* __restrict__ Wq,
                                                     const float* __restrict__ Wk,
                                                     const float* __restrict__ Wv,
                                                     const float* __restrict__ Wo,
                                                     unsigned short* __restrict__ ws) {
    const int xi = blockIdx.x;   // 0..255
    const int z  = blockIdx.y;   // 0..3
    const int t  = threadIdx.x;
    __shared__ __align__(16) unsigned short tile[64][72];

    const float* src; unsigned short* dst;
    int inCols, inBase, outBase;
    if (z < 3) {
        src = (z == 0) ? Wq : (z == 1) ? Wk : Wv;
        dst = ws + ((z == 0) ? OFF_WQT : (z == 1) ? OFF_WKT : OFF_WVT);
        inCols = 64;
        inBase = xi * 64 * 64;
        const int h = xi >> 4, dt = xi & 15;
        outBase = h * 65536 + dt * 64;
    } else {
        src = Wo; dst = ws + OFF_WOT;
        inCols = 1024;
        const int et = xi >> 4, dt = xi & 15;
        inBase  = (dt * 64) * 1024 + et * 64;
        outBase = (et * 64) * 1024 + dt * 64;
    }
#pragma unroll
    for (int v = 0; v < 4; ++v) {
        const int flat = v * 256 + t;
        const int i = flat >> 4, j4 = (flat & 15) * 4;
        const float4 val = *(const float4*)(src + inBase + i * inCols + j4);
        tile[i][j4 + 0] = f2bf(val.x);
        tile[i][j4 + 1] = f2bf(val.y);
        tile[i][j4 + 2] = f2bf(val.z);
        tile[i][j4 + 3] = f2bf(val.w);
    }
    __syncthreads();
    const int j = t >> 2, iseg = (t & 3) * 16;
    u16x8 p0, p1;
#pragma unroll
    for (int u = 0; u < 8; ++u) p0[u] = tile[iseg + u][j];
#pragma unroll
    for (int u = 0; u < 8; ++u) p1[u] = tile[iseg + 8 + u][j];
    *(u16x8*)(dst + outBase + (size_t)j * 1024 + iseg)     = p0;
    *(u16x8*)(dst + outBase + (size_t)j * 1024 + iseg + 8) = p1;
}

// ---------------- GEMM mainloop: C(128x128) = A(128x1024) * B^T(128x1024)^T ----------------
// global_load_lds staging, 3 buffers, 3-deep prefetch, counted-vmcnt barriers.
// Per k-step: 4 gload16/wave -> steady state 12 in flight, wait vmcnt(8).
// lds must hold 3 * 8192 elements (48 KB).
DEVI void gemm_tile_128x128(const unsigned short* __restrict__ A,
                            const unsigned short* __restrict__ Bw,
                            unsigned short* lds,
                            f32x4 acc[2][8]) {
    const int lane = threadIdx.x & 63;
    const int w    = threadIdx.x >> 6;
    const int lr = lane & 15, lg = lane >> 4;
    const unsigned short* a0 = A  + (size_t)((w * 2 + 0) * 16 + lr) * D_ + lg * 8;
    const unsigned short* a1 = A  + (size_t)((w * 2 + 1) * 16 + lr) * D_ + lg * 8;
    const unsigned short* b0 = Bw + (size_t)((w * 2 + 0) * 16 + lr) * D_ + lg * 8;
    const unsigned short* b1 = Bw + (size_t)((w * 2 + 1) * 16 + lr) * D_ + lg * 8;
    const int oA0 = (w * 2 + 0) * 512, oA1 = (w * 2 + 1) * 512;
    const int oB0 = 4096 + oA0,        oB1 = 4096 + oA1;

    auto stage = [&](int ks, int bufi) {
        unsigned short* base = lds + bufi * 8192;
        gload16(a0 + ks * 32, base + oA0);
        gload16(a1 + ks * 32, base + oA1);
        gload16(b0 + ks * 32, base + oB0);
        gload16(b1 + ks * 32, base + oB1);
    };

    stage(0, 0); stage(1, 1); stage(2, 2);
    for (int ks = 0; ks < 32; ++ks) {
        if (ks < 30)       vm_barrier<8>();   // tile ks landed; ks+1, ks+2 in flight
        else if (ks == 30) vm_barrier<4>();
        else               vm_barrier<0>();
        const unsigned short* base = lds + (ks % 3) * 8192;
        bh8 af0 = *(const bh8*)(base + (w * 2 + 0) * 512 + lane * 8);
        bh8 af1 = *(const bh8*)(base + (w * 2 + 1) * 512 + lane * 8);
#pragma unroll
        for (int nt = 0; nt < 8; ++nt) {
            bh8 bf = *(const bh8*)(base + 4096 + nt * 512 + lane * 8);
            acc[0][nt] = mfma16(af0, bf, acc[0][nt]);
            acc[1][nt] = mfma16(af1, bf, acc[1][nt]);
        }
        post_barrier();                        // all waves done reading buf[ks%3]
        if (ks + 3 < 32) stage(ks + 3, ks % 3);
    }
}

// ---------------- fused QKV projection: C[4096,3072] = XB * [WqT;WkT;WvT]^T ----------------
__global__ __launch_bounds__(256, 3) void k_qkv(unsigned short* __restrict__ ws,
                                                const float* __restrict__ bq,
                                                const float* __restrict__ bk,
                                                const float* __restrict__ bv) {
    const int stile = blockIdx.x;   // 0..31 (128 rows each)
    const int ntile = blockIdx.y;   // 0..23 (128 cols each of 3072)
    const int row0  = stile * 128;
    const unsigned short* A  = ws + OFF_XB  + (size_t)row0 * D_;
    const unsigned short* Bw = ws + OFF_WQT + (size_t)ntile * 128 * D_;

    __shared__ __align__(16) unsigned short lds[3 * 8192];
    f32x4 acc[2][8];
#pragma unroll
    for (int i = 0; i < 2; ++i)
#pragma unroll
        for (int j = 0; j < 8; ++j) acc[i][j] = (f32x4){0.f, 0.f, 0.f, 0.f};

    gemm_tile_128x128(A, Bw, lds, acc);

    const int lane = threadIdx.x & 63, w = threadIdx.x >> 6;
    const int lr = lane & 15, lg = lane >> 4;
    const int srow0 = row0 + w * 32;
    const int b     = srow0 >> 11;
    const int sl0   = srow0 & (S_ - 1);
#pragma unroll
    for (int mt = 0; mt < 2; ++mt) {
#pragma unroll
        for (int nt = 0; nt < 8; ++nt) {
            const int gcol = ntile * 128 + nt * 16;
            const int mat  = gcol >> 10;
            const int h    = (gcol >> 6) & 15;
            const int e    = (gcol & 63) + lr;
            const int bh   = b * H_ + h;
            const float bia = ((mat == 0) ? bq : (mat == 1) ? bk : bv)[h * 64 + e];
            if (mat == 2) {
                u16x4 pk;
#pragma unroll
                for (int r = 0; r < 4; ++r) pk[r] = f2bf(acc[mt][nt][r] + bia);
                const int sl = sl0 + mt * 16 + lg * 4;
                *(u16x4*)(ws + OFF_VT + ((size_t)(bh * E_ + e)) * S_ + sl) = pk;
            } else if (mat == 0) {
#pragma unroll
                for (int r = 0; r < 4; ++r) {
                    const int sl = sl0 + mt * 16 + lg * 4 + r;
                    ws[OFF_Q + ((size_t)bh * S_ + sl) * E_ + e] =
                        f2bf((acc[mt][nt][r] + bia) * 0.1803368801f);  // 1/8 * log2(e)
                }
            } else {
#pragma unroll
                for (int r = 0; r < 4; ++r) {
                    const int sl = sl0 + mt * 16 + lg * 4 + r;
                    ws[OFF_K + ((size_t)bh * S_ + sl) * E_ + e] = f2bf(acc[mt][nt][r] + bia);
                }
            }
        }
    }
}

// ---------------- flash attention (causal), 64-row q-tiles, 16 rows/wave ----------------
// XCD-bh swizzle: flat%8 == XCD (round-robin) -> each XCD sees only 4 bh values
// -> its K/V working set = 4 * 512KB = 2MB, fits the 4MB per-XCD L2.
__global__ __launch_bounds__(256, 4) void k_attn(unsigned short* __restrict__ ws) {
    const int flat = blockIdx.x;          // 0..1023
    const int j    = flat & 31;
    const int qt   = 31 - (flat >> 5);    // heavy tiles first
    const int bh   = (j & 7) * 4 + (j >> 3);
    const int lane = threadIdx.x & 63, w = threadIdx.x >> 6;
    const int lr = lane & 15, lg = lane >> 4;
    const unsigned short* Qp = ws + OFF_Q  + (size_t)bh * S_ * E_;
    const unsigned short* Kp = ws + OFF_K  + (size_t)bh * S_ * E_;
    const unsigned short* Vp = ws + OFF_VT + (size_t)bh * E_ * S_;
    __shared__ __align__(16) unsigned short ldsK[2][8 * 512];
    __shared__ __align__(16) unsigned short ldsV[2][8 * 512];
    __shared__ __align__(16) unsigned short ldsP[4 * 1024];   // per-wave 16x64 P (wave-private)

    const int qbase = qt * 64 + w * 16;   // this wave's 16 q rows
    bh8 qf[2];
#pragma unroll
    for (int kg = 0; kg < 2; ++kg)
        qf[kg] = *(const bh8*)(Qp + (size_t)(qbase + lr) * E_ + kg * 32 + lg * 8);

    f32x4 o[4];
    float m[4], l[4];
#pragma unroll
    for (int i = 0; i < 4; ++i) {
        o[i] = (f32x4){0.f, 0.f, 0.f, 0.f};
        m[i] = -3.0e38f; l[i] = 0.f;
    }

    auto stage = [&](int kt, int bufi) {
        const int sk0 = kt * 64;
#pragma unroll
        for (int u = 0; u < 2; ++u) {
            const int blk = w * 2 + u;
            const int ct = blk >> 1, kg = blk & 1;
            gload16(Kp + (size_t)(sk0 + ct * 16 + lr) * E_ + kg * 32 + lg * 8,
                    &ldsK[bufi][blk * 512]);
            gload16(Vp + (size_t)(ct * 16 + lr) * S_ + sk0 + kg * 32 + lg * 8,
                    &ldsV[bufi][blk * 512]);
        }
    };

    unsigned short* Pw = ldsP + w * 1024;

    stage(0, 0);
    if (qt >= 1) stage(1, 1);

    for (int kt = 0; kt <= qt; ++kt) {
        if (kt < qt) vm_barrier<4>();   // tile kt landed; kt+1 in flight
        else         vm_barrier<0>();
        const int cur = kt & 1;
        const int sk0 = kt * 64;
        const unsigned short* Kc = ldsK[cur];
        const unsigned short* Vc = ldsV[cur];

        // S = Q K^T (Q pre-scaled by 0.125*log2e -> scores in log2 domain)
        f32x4 sc[4];
#pragma unroll
        for (int ct = 0; ct < 4; ++ct) sc[ct] = (f32x4){0.f, 0.f, 0.f, 0.f};
#pragma unroll
        for (int ct = 0; ct < 4; ++ct)
#pragma unroll
            for (int kg = 0; kg < 2; ++kg) {
                bh8 kf = *(const bh8*)(Kc + (ct * 2 + kg) * 512 + lane * 8);
                sc[ct] = mfma16(qf[kg], kf, sc[ct]);
            }
        // causal mask: only the diagonal tile needs it (kt == qt)
        if (kt == qt) {
#pragma unroll
            for (int ct = 0; ct < 4; ++ct) {
                const int skc = sk0 + ct * 16 + lr;
#pragma unroll
                for (int r = 0; r < 4; ++r) {
                    const int sq = qbase + lg * 4 + r;
                    if (skc > sq) sc[ct][r] = -3.0e38f;
                }
            }
        }
        // online softmax: row max over 16 lanes
        float mx[4];
#pragma unroll
        for (int r = 0; r < 4; ++r) {
            float v = fmaxf(fmaxf(sc[0][r], sc[1][r]), fmaxf(sc[2][r], sc[3][r]));
            mx[r] = redmax16(v);
        }
        bool need = false;
#pragma unroll
        for (int r = 0; r < 4; ++r) need |= (mx[r] > m[r]);
        if (__any(need)) {   // rescale is identity when mx<=m for all rows
#pragma unroll
            for (int r = 0; r < 4; ++r) {
                const float mn = fmaxf(m[r], mx[r]);
                const float sf = __builtin_amdgcn_exp2f(m[r] - mn);
                m[r] = mn;
                l[r] *= sf;
#pragma unroll
                for (int et = 0; et < 4; ++et) o[et][r] *= sf;
            }
        }
        // P = exp2(S - m), row sums
        float rs[4];
#pragma unroll
        for (int r = 0; r < 4; ++r) rs[r] = 0.f;
#pragma unroll
        for (int ct = 0; ct < 4; ++ct)
#pragma unroll
            for (int r = 0; r < 4; ++r) {
                float p = __builtin_amdgcn_exp2f(sc[ct][r] - m[r]);
                sc[ct][r] = p;
                rs[r] += p;
            }
#pragma unroll
        for (int r = 0; r < 4; ++r) l[r] += redsum16(rs[r]);
        // write P (bf16) into per-wave LDS in A-frag order (wave-private, lgkm-ordered)
#pragma unroll
        for (int ct = 0; ct < 4; ++ct) {
            const int blk = ct >> 1;
            const int lanep = ((ct & 1) * 2 + (lr >> 3)) * 16;
            const int elem = lr & 7;
#pragma unroll
            for (int r = 0; r < 4; ++r)
                Pw[blk * 512 + (lanep + lg * 4 + r) * 8 + elem] = f2bf(sc[ct][r]);
        }
        // O += P V
#pragma unroll
        for (int skg = 0; skg < 2; ++skg) {
            bh8 pf = *(const bh8*)(Pw + skg * 512 + lane * 8);
#pragma unroll
            for (int et = 0; et < 4; ++et) {
                bh8 vf = *(const bh8*)(Vc + (et * 2 + skg) * 512 + lane * 8);
                o[et] = mfma16(pf, vf, o[et]);
            }
        }
        post_barrier();                       // all waves done reading buf[cur]
        if (kt + 2 <= qt) stage(kt + 2, cur); // refill the buffer just freed
    }
    // epilogue: O/l -> concat layout [B,S,H*64]
    const int b = bh >> 4, hh = bh & 15;
#pragma unroll
    for (int r = 0; r < 4; ++r) {
        const float inv = 1.0f / l[r];
        const int s = qbase + lg * 4 + r;
#pragma unroll
        for (int et = 0; et < 4; ++et)
            ws[OFF_O + ((size_t)(b * S_ + s)) * D_ + hh * E_ + et * 16 + lr] =
                f2bf(o[et][r] * inv);
    }
}

// ---------------- output projection: C[4096,1024] = O * WoT^T ----------------
__global__ __launch_bounds__(256, 3) void k_oproj(const unsigned short* __restrict__ ws,
                                                  const float* __restrict__ bo,
                                                  float* __restrict__ out) {
    const int stile = blockIdx.x;   // 0..31
    const int ntile = blockIdx.y;   // 0..7 (128 cols each)
    const unsigned short* A  = ws + OFF_O   + (size_t)stile * 128 * D_;
    const unsigned short* Bw = ws + OFF_WOT + (size_t)ntile * 128 * D_;
    __shared__ __align__(16) unsigned short lds[3 * 8192];
    f32x4 acc[2][8];
#pragma unroll
    for (int i = 0; i < 2; ++i)
#pragma unroll
        for (int j = 0; j < 8; ++j) acc[i][j] = (f32x4){0.f, 0.f, 0.f, 0.f};

    gemm_tile_128x128(A, Bw, lds, acc);

    const int lane = threadIdx.x & 63, w = threadIdx.x >> 6;
    const int lr = lane & 15, lg = lane >> 4;
    const int r0 = stile * 128 + w * 32;
#pragma unroll
    for (int mt = 0; mt < 2; ++mt)
#pragma unroll
        for (int nt = 0; nt < 8; ++nt) {
            const int e = ntile * 128 + nt * 16 + lr;
            const float bia = bo[e];
#pragma unroll
            for (int r = 0; r < 4; ++r)
                out[(size_t)(r0 + mt * 16 + lg * 4 + r) * D_ + e] = acc[mt][nt][r] + bia;
        }
}

extern "C" void kernel_launch(void* const* d_in, const int* in_sizes, int n_in,
                              void* d_out, int out_size, void* d_ws, size_t ws_size,
                              hipStream_t stream) {
    const float* x  = (const float*)d_in[0];
    const float* Wq = (const float*)d_in[1];
    const float* bq = (const float*)d_in[2];
    const float* Wk = (const float*)d_in[3];
    const float* bk = (const float*)d_in[4];
    const float* Wv = (const float*)d_in[5];
    const float* bv = (const float*)d_in[6];
    const float* Wo = (const float*)d_in[7];
    const float* bo = (const float*)d_in[8];
    float* out = (float*)d_out;
    unsigned short* ws = (unsigned short*)d_ws;

    k_convert_x<<<dim3((B_ * S_ * D_) / 4 / 256), 256, 0, stream>>>(x, ws);
    k_transpose_w<<<dim3(256, 4), 256, 0, stream>>>(Wq, Wk, Wv, Wo, ws);
    k_qkv<<<dim3(32, 24), 256, 0, stream>>>(ws, bq, bk, bv);
    k_attn<<<dim3(1024), 256, 0, stream>>>(ws);
    k_oproj<<<dim3(32, 8), 256, 0, stream>>>(ws, bo, out);
}

// Round 7
// 129.047 us; speedup vs baseline: 3.5028x; 1.1147x over previous
//
#include <hip/hip_runtime.h>
#include <stdint.h>

typedef __attribute__((ext_vector_type(8))) short bh8;       // 8 x bf16 (4 VGPR)
typedef __attribute__((ext_vector_type(4))) float f32x4;
typedef __attribute__((ext_vector_type(4))) unsigned short u16x4;
typedef __attribute__((ext_vector_type(8))) unsigned short u16x8;
typedef __attribute__((ext_vector_type(2))) unsigned int u32x2;

#define DEVI static __device__ __forceinline__

constexpr int B_ = 2, S_ = 2048, D_ = 1024, H_ = 16, E_ = 64;

// workspace layout (elements of ushort/bf16)
constexpr size_t OFF_XB  = 0;                              // x as bf16 [B*S, D]
constexpr size_t OFF_WQT = OFF_XB  + (size_t)B_*S_*D_;     // WqT [H, E, D]  } contiguous
constexpr size_t OFF_WKT = OFF_WQT + (size_t)H_*E_*D_;     // WkT [H, E, D]  } = one
constexpr size_t OFF_WVT = OFF_WKT + (size_t)H_*E_*D_;     // WvT [H, E, D]  } [3072,1024]
constexpr size_t OFF_WOT = OFF_WVT + (size_t)H_*E_*D_;     // WoT [D, D]
constexpr size_t OFF_Q   = OFF_WOT + (size_t)D_*D_;        // Q^T [B*H, E, S] (pre-scaled by 0.125*log2e)
constexpr size_t OFF_K   = OFF_Q   + (size_t)B_*H_*S_*E_;  // [B*H, S, E]
constexpr size_t OFF_VT  = OFF_K   + (size_t)B_*H_*S_*E_;  // [B*H, E, S]
constexpr size_t OFF_O   = OFF_VT  + (size_t)B_*H_*S_*E_;  // attn out concat [B*S, D]

DEVI unsigned short f2bf(float f) {
    union { float f; unsigned u; } v; v.f = f;
    unsigned u = v.u;
    return (unsigned short)((u + 0x7fffu + ((u >> 16) & 1u)) >> 16);
}

DEVI unsigned cvt_pk_bf16(float lo, float hi) {   // packs {lo,hi} -> 2 bf16 in one u32
    unsigned r;
    asm("v_cvt_pk_bf16_f32 %0, %1, %2" : "=v"(r) : "v"(lo), "v"(hi));
    return r;
}

DEVI void gload16(const void* g, void* l) {
    __builtin_amdgcn_global_load_lds(
        (const __attribute__((address_space(1))) unsigned int*)g,
        (__attribute__((address_space(3))) unsigned int*)l, 16, 0, 0);
}

DEVI f32x4 mfma16(bh8 a, bh8 b, f32x4 c) {
    return __builtin_amdgcn_mfma_f32_16x16x32_bf16(a, b, c, 0, 0, 0);
}

// counted-vmcnt barrier: prefetched loads stay in flight across the barrier.
template<int N> DEVI void vm_barrier() {
    asm volatile("s_waitcnt vmcnt(%0)" :: "i"(N) : "memory");
    __builtin_amdgcn_s_barrier();
    __builtin_amdgcn_sched_barrier(0);
}
DEVI void post_barrier() {
    __builtin_amdgcn_sched_barrier(0);
    __builtin_amdgcn_s_barrier();
    __builtin_amdgcn_sched_barrier(0);
}

// ---------------- prep: x -> bf16 ----------------
__global__ __launch_bounds__(256) void k_convert_x(const float* __restrict__ x,
                                                   unsigned short* __restrict__ ws) {
    const int i = blockIdx.x * 256 + threadIdx.x;   // one float4 each; n4 = 1048576
    const float4 v = ((const float4*)x)[i];
    u16x4 o = { f2bf(v.x), f2bf(v.y), f2bf(v.z), f2bf(v.w) };
    *(u16x4*)(ws + OFF_XB + (size_t)i * 4) = o;
}

// ---------------- prep: weights -> bf16, transposed ----------------
__global__ __launch_bounds__(256) void k_transpose_w(const float* __restrict__ Wq,
                                                     const float* __restrict__ Wk,
                                                     const float* __restrict__ Wv,
                                                     const float* __restrict__ Wo,
                                                     unsigned short* __restrict__ ws) {
    const int xi = blockIdx.x;   // 0..255
    const int z  = blockIdx.y;   // 0..3
    const int t  = threadIdx.x;
    __shared__ __align__(16) unsigned short tile[64][72];

    const float* src; unsigned short* dst;
    int inCols, inBase, outBase;
    if (z < 3) {
        src = (z == 0) ? Wq : (z == 1) ? Wk : Wv;
        dst = ws + ((z == 0) ? OFF_WQT : (z == 1) ? OFF_WKT : OFF_WVT);
        inCols = 64;
        inBase = xi * 64 * 64;
        const int h = xi >> 4, dt = xi & 15;
        outBase = h * 65536 + dt * 64;
    } else {
        src = Wo; dst = ws + OFF_WOT;
        inCols = 1024;
        const int et = xi >> 4, dt = xi & 15;
        inBase  = (dt * 64) * 1024 + et * 64;
        outBase = (et * 64) * 1024 + dt * 64;
    }
#pragma unroll
    for (int v = 0; v < 4; ++v) {
        const int flat = v * 256 + t;
        const int i = flat >> 4, j4 = (flat & 15) * 4;
        const float4 val = *(const float4*)(src + inBase + i * inCols + j4);
        tile[i][j4 + 0] = f2bf(val.x);
        tile[i][j4 + 1] = f2bf(val.y);
        tile[i][j4 + 2] = f2bf(val.z);
        tile[i][j4 + 3] = f2bf(val.w);
    }
    __syncthreads();
    const int j = t >> 2, iseg = (t & 3) * 16;
    u16x8 p0, p1;
#pragma unroll
    for (int u = 0; u < 8; ++u) p0[u] = tile[iseg + u][j];
#pragma unroll
    for (int u = 0; u < 8; ++u) p1[u] = tile[iseg + 8 + u][j];
    *(u16x8*)(dst + outBase + (size_t)j * 1024 + iseg)     = p0;
    *(u16x8*)(dst + outBase + (size_t)j * 1024 + iseg + 8) = p1;
}

// ---------------- GEMM mainloop: C(128x128) = A(128x1024) * B^T(128x1024)^T ----------------
// global_load_lds staging, 3 buffers, 3-deep prefetch, counted-vmcnt barriers.
DEVI void gemm_tile_128x128(const unsigned short* __restrict__ A,
                            const unsigned short* __restrict__ Bw,
                            unsigned short* lds,
                            f32x4 acc[2][8]) {
    const int lane = threadIdx.x & 63;
    const int w    = threadIdx.x >> 6;
    const int lr = lane & 15, lg = lane >> 4;
    const unsigned short* a0 = A  + (size_t)((w * 2 + 0) * 16 + lr) * D_ + lg * 8;
    const unsigned short* a1 = A  + (size_t)((w * 2 + 1) * 16 + lr) * D_ + lg * 8;
    const unsigned short* b0 = Bw + (size_t)((w * 2 + 0) * 16 + lr) * D_ + lg * 8;
    const unsigned short* b1 = Bw + (size_t)((w * 2 + 1) * 16 + lr) * D_ + lg * 8;
    const int oA0 = (w * 2 + 0) * 512, oA1 = (w * 2 + 1) * 512;
    const int oB0 = 4096 + oA0,        oB1 = 4096 + oA1;

    auto stage = [&](int ks, int bufi) {
        unsigned short* base = lds + bufi * 8192;
        gload16(a0 + ks * 32, base + oA0);
        gload16(a1 + ks * 32, base + oA1);
        gload16(b0 + ks * 32, base + oB0);
        gload16(b1 + ks * 32, base + oB1);
    };

    stage(0, 0); stage(1, 1); stage(2, 2);
    for (int ks = 0; ks < 32; ++ks) {
        if (ks < 30)       vm_barrier<8>();
        else if (ks == 30) vm_barrier<4>();
        else               vm_barrier<0>();
        const unsigned short* base = lds + (ks % 3) * 8192;
        bh8 af0 = *(const bh8*)(base + (w * 2 + 0) * 512 + lane * 8);
        bh8 af1 = *(const bh8*)(base + (w * 2 + 1) * 512 + lane * 8);
#pragma unroll
        for (int nt = 0; nt < 8; ++nt) {
            bh8 bf = *(const bh8*)(base + 4096 + nt * 512 + lane * 8);
            acc[0][nt] = mfma16(af0, bf, acc[0][nt]);
            acc[1][nt] = mfma16(af1, bf, acc[1][nt]);
        }
        post_barrier();
        if (ks + 3 < 32) stage(ks + 3, ks % 3);
    }
}

// ---------------- fused QKV projection: C[4096,3072] = XB * [WqT;WkT;WvT]^T ----------------
__global__ __launch_bounds__(256, 3) void k_qkv(unsigned short* __restrict__ ws,
                                                const float* __restrict__ bq,
                                                const float* __restrict__ bk,
                                                const float* __restrict__ bv) {
    const int stile = blockIdx.x;   // 0..31 (128 rows each)
    const int ntile = blockIdx.y;   // 0..23 (128 cols each of 3072)
    const int row0  = stile * 128;
    const unsigned short* A  = ws + OFF_XB  + (size_t)row0 * D_;
    const unsigned short* Bw = ws + OFF_WQT + (size_t)ntile * 128 * D_;

    __shared__ __align__(16) unsigned short lds[3 * 8192];
    f32x4 acc[2][8];
#pragma unroll
    for (int i = 0; i < 2; ++i)
#pragma unroll
        for (int j = 0; j < 8; ++j) acc[i][j] = (f32x4){0.f, 0.f, 0.f, 0.f};

    gemm_tile_128x128(A, Bw, lds, acc);

    const int lane = threadIdx.x & 63, w = threadIdx.x >> 6;
    const int lr = lane & 15, lg = lane >> 4;
    const int srow0 = row0 + w * 32;
    const int b     = srow0 >> 11;
    const int sl0   = srow0 & (S_ - 1);
#pragma unroll
    for (int mt = 0; mt < 2; ++mt) {
#pragma unroll
        for (int nt = 0; nt < 8; ++nt) {
            const int gcol = ntile * 128 + nt * 16;
            const int mat  = gcol >> 10;
            const int h    = (gcol >> 6) & 15;
            const int e    = (gcol & 63) + lr;
            const int bh   = b * H_ + h;
            const float bia = ((mat == 0) ? bq : (mat == 1) ? bk : bv)[h * 64 + e];
            if (mat == 0) {        // Q^T [BH][E][S], packed along s, pre-scaled
                u16x4 pk;
#pragma unroll
                for (int r = 0; r < 4; ++r)
                    pk[r] = f2bf((acc[mt][nt][r] + bia) * 0.1803368801f);  // 1/8*log2(e)
                const int sl = sl0 + mt * 16 + lg * 4;
                *(u16x4*)(ws + OFF_Q + ((size_t)(bh * E_ + e)) * S_ + sl) = pk;
            } else if (mat == 2) { // V^T [BH][E][S]
                u16x4 pk;
#pragma unroll
                for (int r = 0; r < 4; ++r) pk[r] = f2bf(acc[mt][nt][r] + bia);
                const int sl = sl0 + mt * 16 + lg * 4;
                *(u16x4*)(ws + OFF_VT + ((size_t)(bh * E_ + e)) * S_ + sl) = pk;
            } else {               // K [BH][S][E]
#pragma unroll
                for (int r = 0; r < 4; ++r) {
                    const int sl = sl0 + mt * 16 + lg * 4 + r;
                    ws[OFF_K + ((size_t)bh * S_ + sl) * E_ + e] = f2bf(acc[mt][nt][r] + bia);
                }
            }
        }
    }
}

// ---------------- flash attention (causal), swapped-QK^T in-lane softmax ----------------
// XCD-bh swizzle keeps each XCD's K/V working set (4 bh = 2MB) in its L2.
// QK^T computed as mfma(K, Q): lane holds P[s_k = ct*16+lg*4+r][q = lane&15]
// -> row-reduce is 15 in-lane ops + 2 shfl; P packs via v_cvt_pk_bf16_f32
// -> 4 ds_write_b64 into A-frag order (reader side unchanged).
__global__ __launch_bounds__(256, 4) void k_attn(unsigned short* __restrict__ ws) {
    const int flat = blockIdx.x;          // 0..1023
    const int j    = flat & 31;
    const int qt   = 31 - (flat >> 5);    // heavy tiles first
    const int bh   = (j & 7) * 4 + (j >> 3);
    const int lane = threadIdx.x & 63, w = threadIdx.x >> 6;
    const int lr = lane & 15, lg = lane >> 4;
    const unsigned short* Qp = ws + OFF_Q  + (size_t)bh * E_ * S_;   // Q^T [E][S]
    const unsigned short* Kp = ws + OFF_K  + (size_t)bh * S_ * E_;
    const unsigned short* Vp = ws + OFF_VT + (size_t)bh * E_ * S_;
    __shared__ __align__(16) unsigned short ldsK[2][8 * 512];
    __shared__ __align__(16) unsigned short ldsV[2][8 * 512];
    __shared__ __align__(16) unsigned short ldsP[4 * 1024];   // per-wave 16x64 P (wave-private)

    const int qbase = qt * 64 + w * 16;   // this wave's 16 q rows
    // Q fragment from Q^T: lane needs Q[qbase+lr][kg*32+lg*8+i] = QT[e][qbase+lr]
    bh8 qf[2];
#pragma unroll
    for (int kg = 0; kg < 2; ++kg) {
        bh8 t;
#pragma unroll
        for (int i = 0; i < 8; ++i)
            t[i] = (short)Qp[(size_t)(kg * 32 + lg * 8 + i) * S_ + qbase + lr];
        qf[kg] = t;
    }

    f32x4 o[4];
    float m = -3.0e38f, l = 0.f;    // per-lane online state for q = lr (replicated over lg)
#pragma unroll
    for (int i = 0; i < 4; ++i) o[i] = (f32x4){0.f, 0.f, 0.f, 0.f};

    auto stage = [&](int kt, int bufi) {
        const int sk0 = kt * 64;
#pragma unroll
        for (int u = 0; u < 2; ++u) {
            const int blk = w * 2 + u;
            const int ct = blk >> 1, kg = blk & 1;
            gload16(Kp + (size_t)(sk0 + ct * 16 + lr) * E_ + kg * 32 + lg * 8,
                    &ldsK[bufi][blk * 512]);
            gload16(Vp + (size_t)(ct * 16 + lr) * S_ + sk0 + kg * 32 + lg * 8,
                    &ldsV[bufi][blk * 512]);
        }
    };

    unsigned short* Pw = ldsP + w * 1024;

    stage(0, 0);
    if (qt >= 1) stage(1, 1);

    for (int kt = 0; kt <= qt; ++kt) {
        if (kt < qt) vm_barrier<4>();
        else         vm_barrier<0>();
        const int cur = kt & 1;
        const unsigned short* Kc = ldsK[cur];
        const unsigned short* Vc = ldsV[cur];

        // S^T = K Q^T (swapped): sc[ct][r] = score[s_k = ct*16+lg*4+r][q = lr]
        f32x4 sc[4];
#pragma unroll
        for (int ct = 0; ct < 4; ++ct) sc[ct] = (f32x4){0.f, 0.f, 0.f, 0.f};
#pragma unroll
        for (int ct = 0; ct < 4; ++ct)
#pragma unroll
            for (int kg = 0; kg < 2; ++kg) {
                bh8 kf = *(const bh8*)(Kc + (ct * 2 + kg) * 512 + lane * 8);
                sc[ct] = mfma16(kf, qf[kg], sc[ct]);
            }
        // causal mask: diagonal tile only; local: s_k = ct*16+lg*4+r, q = w*16+lr
        if (kt == qt) {
#pragma unroll
            for (int ct = 0; ct < 4; ++ct) {
                const int skl = ct * 16 + lg * 4;
#pragma unroll
                for (int r = 0; r < 4; ++r)
                    if (skl + r > w * 16 + lr) sc[ct][r] = -3.0e38f;
            }
        }
        // column (q) max: 15 in-lane fmax + 2 shfl
        float mx = fmaxf(fmaxf(sc[0][0], sc[0][1]), fmaxf(sc[0][2], sc[0][3]));
#pragma unroll
        for (int ct = 1; ct < 4; ++ct)
            mx = fmaxf(mx, fmaxf(fmaxf(sc[ct][0], sc[ct][1]),
                                 fmaxf(sc[ct][2], sc[ct][3])));
        mx = fmaxf(mx, __shfl_xor(mx, 16, 64));
        mx = fmaxf(mx, __shfl_xor(mx, 32, 64));
        // defer-max (T13): rescale only when max grew by > 8 (log2 domain)
        const bool need = mx > m + 8.0f;
        if (__any(need)) {
            const float mn = need ? mx : m;
            const float sf = __builtin_amdgcn_exp2f(m - mn);   // 1.0 when !need
            m = mn;
            l *= sf;
#pragma unroll
            for (int r = 0; r < 4; ++r) {
                const float sfq = __shfl(sf, (lane & 48) + lg * 4 + r, 64);
#pragma unroll
                for (int et = 0; et < 4; ++et) o[et][r] *= sfq;
            }
        }
        // P = exp2(S - m), partial sum in-lane
        float rs = 0.f;
#pragma unroll
        for (int ct = 0; ct < 4; ++ct)
#pragma unroll
            for (int r = 0; r < 4; ++r) {
                float p = __builtin_amdgcn_exp2f(sc[ct][r] - m);
                sc[ct][r] = p;
                rs += p;
            }
        rs += __shfl_xor(rs, 16, 64);
        rs += __shfl_xor(rs, 32, 64);
        l += rs;
        // pack P (cvt_pk) and write A-frag order: 4 x ds_write_b64
#pragma unroll
        for (int ct = 0; ct < 4; ++ct) {
            u32x2 pk = { cvt_pk_bf16(sc[ct][0], sc[ct][1]),
                         cvt_pk_bf16(sc[ct][2], sc[ct][3]) };
            const int addr = (ct >> 1) * 512 +
                             ((((ct & 1) * 2) + (lg >> 1)) * 16 + lr) * 8 + (lg & 1) * 4;
            *(u32x2*)(Pw + addr) = pk;
        }
        // O += P V  (wave-private P; lgkm-ordered, no barrier)
#pragma unroll
        for (int skg = 0; skg < 2; ++skg) {
            bh8 pf = *(const bh8*)(Pw + skg * 512 + lane * 8);
#pragma unroll
            for (int et = 0; et < 4; ++et) {
                bh8 vf = *(const bh8*)(Vc + (et * 2 + skg) * 512 + lane * 8);
                o[et] = mfma16(pf, vf, o[et]);
            }
        }
        post_barrier();
        if (kt + 2 <= qt) stage(kt + 2, cur);
    }
    // epilogue: O/l -> concat layout [B,S,H*64]; l lives at lane with lr = q
    const int b = bh >> 4, hh = bh & 15;
#pragma unroll
    for (int r = 0; r < 4; ++r) {
        const float lq = __shfl(l, (lane & 48) + lg * 4 + r, 64);
        const float inv = 1.0f / lq;
        const int s = qbase + lg * 4 + r;
#pragma unroll
        for (int et = 0; et < 4; ++et)
            ws[OFF_O + ((size_t)(b * S_ + s)) * D_ + hh * E_ + et * 16 + lr] =
                f2bf(o[et][r] * inv);
    }
}

// ---------------- output projection: C[4096,1024] = O * WoT^T ----------------
__global__ __launch_bounds__(256, 3) void k_oproj(const unsigned short* __restrict__ ws,
                                                  const float* __restrict__ bo,
                                                  float* __restrict__ out) {
    const int stile = blockIdx.x;   // 0..31
    const int ntile = blockIdx.y;   // 0..7 (128 cols each)
    const unsigned short* A  = ws + OFF_O   + (size_t)stile * 128 * D_;
    const unsigned short* Bw = ws + OFF_WOT + (size_t)ntile * 128 * D_;
    __shared__ __align__(16) unsigned short lds[3 * 8192];
    f32x4 acc[2][8];
#pragma unroll
    for (int i = 0; i < 2; ++i)
#pragma unroll
        for (int j = 0; j < 8; ++j) acc[i][j] = (f32x4){0.f, 0.f, 0.f, 0.f};

    gemm_tile_128x128(A, Bw, lds, acc);

    const int lane = threadIdx.x & 63, w = threadIdx.x >> 6;
    const int lr = lane & 15, lg = lane >> 4;
    const int r0 = stile * 128 + w * 32;
#pragma unroll
    for (int mt = 0; mt < 2; ++mt)
#pragma unroll
        for (int nt = 0; nt < 8; ++nt) {
            const int e = ntile * 128 + nt * 16 + lr;
            const float bia = bo[e];
#pragma unroll
            for (int r = 0; r < 4; ++r)
                out[(size_t)(r0 + mt * 16 + lg * 4 + r) * D_ + e] = acc[mt][nt][r] + bia;
        }
}

extern "C" void kernel_launch(void* const* d_in, const int* in_sizes, int n_in,
                              void* d_out, int out_size, void* d_ws, size_t ws_size,
                              hipStream_t stream) {
    const float* x  = (const float*)d_in[0];
    const float* Wq = (const float*)d_in[1];
    const float* bq = (const float*)d_in[2];
    const float* Wk = (const float*)d_in[3];
    const float* bk = (const float*)d_in[4];
    const float* Wv = (const float*)d_in[5];
    const float* bv = (const float*)d_in[6];
    const float* Wo = (const float*)d_in[7];
    const float* bo = (const float*)d_in[8];
    float* out = (float*)d_out;
    unsigned short* ws = (unsigned short*)d_ws;

    k_convert_x<<<dim3((B_ * S_ * D_) / 4 / 256), 256, 0, stream>>>(x, ws);
    k_transpose_w<<<dim3(256, 4), 256, 0, stream>>>(Wq, Wk, Wv, Wo, ws);
    k_qkv<<<dim3(32, 24), 256, 0, stream>>>(ws, bq, bk, bv);
    k_attn<<<dim3(1024), 256, 0, stream>>>(ws);
    k_oproj<<<dim3(32, 8), 256, 0, stream>>>(ws, bo, out);
}